// Round 6
// baseline (1446.150 us; speedup 1.0000x reference)
//
#include <hip/hip_runtime.h>
#include <hip/hip_fp16.h>
#include <cstdint>
#include <cstddef>

// Problem constants (fixed by the reference)
#define HIDDEN 4096
#define INTER  11008
#define NTOK   4096          // B*S = 4*1024
#define NG1    (HIDDEN/64)   // 64 groups along hidden (= K-steps for gateup)
#define NG2    (INTER/64)    // 172 groups along inter (= K-steps for down)

typedef _Float16 f16;
typedef _Float16 f16x8 __attribute__((ext_vector_type(8)));
typedef float    f32x4 __attribute__((ext_vector_type(4)));

// ---- async global->LDS, 16B per lane (dest must be wave-uniform base + lane*16)
__device__ __forceinline__ void g2lds16(const void* g, void* l) {
  __builtin_amdgcn_global_load_lds(
      (const __attribute__((address_space(1))) uint32_t*)g,
      (__attribute__((address_space(3))) uint32_t*)l, 16, 0, 0);
}

// ---- dequant one storage int32 (value in [0,256) = 2 nibbles) -> 2 f16
__device__ __forceinline__ uint32_t dq2(uint32_t b, __half2 s2, __half2 nzs) {
  uint32_t qb = 0x64006400u | (b >> 4) | ((b & 0xFu) << 16);
  __half2 hq = __builtin_bit_cast(__half2, qb);
  __half2 t  = __hsub2(hq, __builtin_bit_cast(__half2, 0x64006400u));
  __half2 wv = __hfma2(t, s2, nzs);
  return __builtin_bit_cast(uint32_t, wv);
}

// ---------------------------------------------------------------- x: fp32->f16
__global__ __launch_bounds__(256) void cvt_x(const float* __restrict__ x,
                                             f16* __restrict__ xh) {
  size_t i = ((size_t)blockIdx.x * 256 + threadIdx.x) * 8;
  float4 a = *(const float4*)(x + i);
  float4 b = *(const float4*)(x + i + 4);
  f16x8 o = {(f16)a.x, (f16)a.y, (f16)a.z, (f16)a.w,
             (f16)b.x, (f16)b.y, (f16)b.z, (f16)b.w};
  *(f16x8*)(xh + i) = o;
}

// ---------------------------------------------- weight dequant pass (once)
__global__ __launch_bounds__(256) void deq_w(const uint32_t* __restrict__ q,
                                             const float* __restrict__ s,
                                             const float* __restrict__ z,
                                             f16* __restrict__ out) {
  int g = blockIdx.x * 256 + threadIdx.x;
  const uint32_t* qp = q + (size_t)g * 32;
  float sf = s[g], zf = z[g];
  __half2 s2 = __float2half2_rn(sf), nzs = __float2half2_rn(-zf * sf);
  f16* op = out + (size_t)g * 64;
#pragma unroll
  for (int i = 0; i < 8; ++i) {
    uint4 w = *(const uint4*)(qp + i * 4);
    uint4 o;
    o.x = dq2(w.x, s2, nzs); o.y = dq2(w.y, s2, nzs);
    o.z = dq2(w.z, s2, nzs); o.w = dq2(w.w, s2, nzs);
    *(uint4*)(op + i * 8) = o;
  }
}

// ============================ FAST PATH: 256-wide tiles =====================
// Geometry (both GEMMs): block 256M x 256N(equiv), BK=64, 8 waves (2M x 4N),
// wave tile 128x64 -> 384 B LDS-read per MFMA (was 512). acc = 128 AGPR.
// LDS = 2 x (A 32K + B 32K) = 128 KB -> 1 block/CU, 8 waves.
// Schedule: stage(t+1 -> other buf) via pure DMA at loop top (flies across
// the whole ~800-cyc compute), ONE __syncthreads per K-step (its vmcnt(0)
// drain is exact: the loads had the full compute to land). Race-free:
// stage(t+1) targets the buffer whose readers finished before the previous
// barrier. No staging VALU, no ds_write in the loop.

// gateup2: h = silu(x Wg^T) * (x Wu^T). B tile = 128 gate rows + 128 up rows.
// Waves wn 0,1 -> gate cols [0,64); wn 2,3 -> up, same cols. Epilogue: gate
// waves write silu(g) f16 into the idle LDS buffer (final compute uses buf1;
// exchange uses buf0 bytes 0..64K), barrier, up waves multiply + store h.
__global__ __launch_bounds__(512, 2) void gemm_gateup2(
    const f16* __restrict__ xh, const f16* __restrict__ wg,
    const f16* __restrict__ wu, f16* __restrict__ h) {
  extern __shared__ char smem[];
  const int tid = threadIdx.x, lane = tid & 63, wave = tid >> 6;
  const int bm = blockIdx.x, bn = blockIdx.y;      // 16 x 86
  const int wm = wave >> 2, wn = wave & 3;

  // ---- staging addressing: thread t covers row (t>>3)+c*64, k8 slot t&7
  const int srow = tid >> 3;
  const int sk8  = (tid & 7) ^ (srow & 7);         // pre-swizzled global k8
  const f16* aptr = xh + (size_t)(bm * 256 + srow) * HIDDEN + sk8 * 8;
  const f16* gptr = wg + (size_t)(bn * 128 + srow) * HIDDEN + sk8 * 8;
  const f16* uptr = wu + (size_t)(bn * 128 + srow) * HIDDEN + sk8 * 8;
  const int soff = tid * 16;

  // ---- fragment-read addressing (wave tile 128M x 64N)
  int abase[8], asel[8];
#pragma unroll
  for (int im = 0; im < 8; ++im) {
    int r = wm * 128 + im * 16 + (lane & 15);
    abase[im] = r * 128; asel[im] = r & 7;
  }
  int bbase[4], bsel[4];
#pragma unroll
  for (int in_ = 0; in_ < 4; ++in_) {
    int r = wn * 64 + in_ * 16 + (lane & 15);      // rows 0-127 gate, 128-255 up
    bbase[in_] = 32768 + r * 128; bsel[in_] = r & 7;
  }
  const int kchunk = lane >> 4;

  f32x4 acc[8][4] = {};

  auto stage = [&](int kt, int pb) {
    char* base = smem + pb * 65536;
    const f16* ap = aptr + (size_t)kt * 64;
#pragma unroll
    for (int i = 0; i < 4; ++i)
      g2lds16(ap + (size_t)i * 64 * HIDDEN, base + soff + i * 8192);
    const f16* gp = gptr + (size_t)kt * 64;
    g2lds16(gp,                           base + 32768 + soff);
    g2lds16(gp + (size_t)64 * HIDDEN,     base + 32768 + soff + 8192);
    const f16* up = uptr + (size_t)kt * 64;
    g2lds16(up,                           base + 32768 + soff + 16384);
    g2lds16(up + (size_t)64 * HIDDEN,     base + 32768 + soff + 24576);
  };
  auto compute = [&](int pb) {
    const char* base = smem + pb * 65536;
#pragma unroll
    for (int ks = 0; ks < 2; ++ks) {
      int kc = ks * 4 + kchunk;
      f16x8 a[8], b[4];
#pragma unroll
      for (int im = 0; im < 8; ++im)
        a[im] = *(const f16x8*)(base + abase[im] + ((kc ^ asel[im]) << 4));
#pragma unroll
      for (int in_ = 0; in_ < 4; ++in_)
        b[in_] = *(const f16x8*)(base + bbase[in_] + ((kc ^ bsel[in_]) << 4));
#pragma unroll
      for (int im = 0; im < 8; ++im)
#pragma unroll
        for (int in_ = 0; in_ < 4; ++in_)
          acc[im][in_] = __builtin_amdgcn_mfma_f32_16x16x32_f16(a[im], b[in_], acc[im][in_], 0, 0, 0);
    }
  };

  // ---- prologue: tile 0 (latency exposed once)
  stage(0, 0);
  __syncthreads();

  // ---- main loop: one barrier per K-step; stage loads fly the whole compute
  for (int kt = 0; kt < NG1 - 1; ++kt) {
    stage(kt + 1, (kt + 1) & 1);
    __builtin_amdgcn_sched_barrier(0);   // pin DMA issues before compute reads
    compute(kt & 1);
    __syncthreads();                      // vmcnt(0)+lgkm: next tile landed
  }
  compute((NG1 - 1) & 1);                 // NG1-1 = 63 -> buf1; buf0 now idle

  // ---- epilogue: silu(g)*u via LDS exchange in buf0 (disjoint from buf1)
  // C/D layout: col=lane&15, row=(lane>>4)*4+r
  const int r0 = (lane >> 4) * 4;
  const int c0 = lane & 15;
  if (wn < 2) {
    char* reg = smem + (wm * 2 + wn) * 16384;      // 16 KB per gate wave
#pragma unroll
    for (int im = 0; im < 8; ++im)
#pragma unroll
      for (int in_ = 0; in_ < 4; ++in_)
#pragma unroll
        for (int r = 0; r < 4; ++r) {
          float g = acc[im][in_][r];
          float sg = g / (1.0f + __expf(-g));
          int rowL = im * 16 + r0 + r, colL = in_ * 16 + c0;
          *(f16*)(reg + rowL * 128 + colL * 2) = (f16)sg;
        }
  }
  __syncthreads();
  if (wn >= 2) {
    const char* reg = smem + (wm * 2 + (wn - 2)) * 16384;
#pragma unroll
    for (int im = 0; im < 8; ++im)
#pragma unroll
      for (int in_ = 0; in_ < 4; ++in_)
#pragma unroll
        for (int r = 0; r < 4; ++r) {
          int rowL = im * 16 + r0 + r, colL = in_ * 16 + c0;
          float sg = (float)*(const f16*)(reg + rowL * 128 + colL * 2);
          float hv = sg * acc[im][in_][r];
          int row = bm * 256 + wm * 128 + rowL;
          int col = bn * 128 + (wn - 2) * 64 + colL;
          h[(size_t)row * INTER + col] = (f16)hv;
        }
  }
}

// down2: out = h Wd^T (fp32). Pure 256x256 tile, same schedule.
__global__ __launch_bounds__(512, 2) void gemm_down2(
    const f16* __restrict__ h, const f16* __restrict__ wd,
    float* __restrict__ out) {
  extern __shared__ char smem[];
  const int tid = threadIdx.x, lane = tid & 63, wave = tid >> 6;
  const int bm = blockIdx.x, bn = blockIdx.y;      // 16 x 16
  const int wm = wave >> 2, wn = wave & 3;

  const int srow = tid >> 3;
  const int sk8  = (tid & 7) ^ (srow & 7);
  const f16* aptr = h  + (size_t)(bm * 256 + srow) * INTER + sk8 * 8;
  const f16* bptr = wd + (size_t)(bn * 256 + srow) * INTER + sk8 * 8;
  const int soff = tid * 16;

  int abase[8], asel[8];
#pragma unroll
  for (int im = 0; im < 8; ++im) {
    int r = wm * 128 + im * 16 + (lane & 15);
    abase[im] = r * 128; asel[im] = r & 7;
  }
  int bbase[4], bsel[4];
#pragma unroll
  for (int in_ = 0; in_ < 4; ++in_) {
    int r = wn * 64 + in_ * 16 + (lane & 15);
    bbase[in_] = 32768 + r * 128; bsel[in_] = r & 7;
  }
  const int kchunk = lane >> 4;

  f32x4 acc[8][4] = {};

  auto stage = [&](int kt, int pb) {
    char* base = smem + pb * 65536;
    const f16* ap = aptr + (size_t)kt * 64;
    const f16* bp = bptr + (size_t)kt * 64;
#pragma unroll
    for (int i = 0; i < 4; ++i) {
      g2lds16(ap + (size_t)i * 64 * INTER, base + soff + i * 8192);
      g2lds16(bp + (size_t)i * 64 * INTER, base + 32768 + soff + i * 8192);
    }
  };
  auto compute = [&](int pb) {
    const char* base = smem + pb * 65536;
#pragma unroll
    for (int ks = 0; ks < 2; ++ks) {
      int kc = ks * 4 + kchunk;
      f16x8 a[8], b[4];
#pragma unroll
      for (int im = 0; im < 8; ++im)
        a[im] = *(const f16x8*)(base + abase[im] + ((kc ^ asel[im]) << 4));
#pragma unroll
      for (int in_ = 0; in_ < 4; ++in_)
        b[in_] = *(const f16x8*)(base + bbase[in_] + ((kc ^ bsel[in_]) << 4));
#pragma unroll
      for (int im = 0; im < 8; ++im)
#pragma unroll
        for (int in_ = 0; in_ < 4; ++in_)
          acc[im][in_] = __builtin_amdgcn_mfma_f32_16x16x32_f16(a[im], b[in_], acc[im][in_], 0, 0, 0);
    }
  };

  stage(0, 0);
  __syncthreads();
  for (int kt = 0; kt < NG2 - 1; ++kt) {
    stage(kt + 1, (kt + 1) & 1);
    __builtin_amdgcn_sched_barrier(0);
    compute(kt & 1);
    __syncthreads();
  }
  compute((NG2 - 1) & 1);

  const int r0 = (lane >> 4) * 4;
  const int c0 = lane & 15;
#pragma unroll
  for (int im = 0; im < 8; ++im)
#pragma unroll
    for (int in_ = 0; in_ < 4; ++in_)
#pragma unroll
      for (int r = 0; r < 4; ++r) {
        int row = bm * 256 + wm * 128 + im * 16 + r0 + r;
        int col = bn * 256 + wn * 64 + in_ * 16 + c0;
        out[(size_t)row * HIDDEN + col] = acc[im][in_][r];
      }
}

// ============================ FALLBACK PATH (round-0, dequant in-GEMM) ======
__global__ __launch_bounds__(512, 4) void gemm_gateup_q(
    const f16* __restrict__ xh,
    const uint32_t* __restrict__ gq, const uint32_t* __restrict__ uq,
    const float* __restrict__ gs, const float* __restrict__ gz,
    const float* __restrict__ us, const float* __restrict__ uz,
    f16* __restrict__ h) {
  extern __shared__ char smem[];
  f16* lA0 = (f16*)smem;
  f16* lA1 = (f16*)(smem + 32768);
  char* lBg = smem + 65536;
  char* lBu = smem + 73728;
  const int tid = threadIdx.x, lane = tid & 63, wave = tid >> 6;
  const int bm = blockIdx.x, bn = blockIdx.y;
  const int wm = wave >> 1, wn = wave & 1;

  const int arow0 = tid >> 3;
  const int ak8s  = (tid & 7) ^ (arow0 & 7);
  const f16* aptr = xh + (size_t)(bm * 256 + arow0) * HIDDEN + ak8s * 8;
  const int aoff = tid * 16;

  const int mat = tid >> 8;
  const int t = tid & 255;
  const int brow0 = t >> 3;
  const uint32_t* qp = (mat ? uq : gq) + (size_t)(bn * 64 + brow0) * (HIDDEN / 2) + (t & 7) * 4;
  const float* sp = (mat ? us : gs) + (size_t)(bn * 64 + brow0) * NG1;
  const float* zp = (mat ? uz : gz) + (size_t)(bn * 64 + brow0) * NG1;
  char* lb = mat ? lBu : lBg;
  const int bws0 = brow0 * 128 + (((t & 7) ^ (brow0 & 7)) << 4);

  int abase[4], asel[4];
#pragma unroll
  for (int im = 0; im < 4; ++im) {
    int r = wm * 64 + im * 16 + (lane & 15);
    abase[im] = r * 128; asel[im] = r & 7;
  }
  int bbase[2], bsel[2];
#pragma unroll
  for (int in_ = 0; in_ < 2; ++in_) {
    int r = wn * 32 + in_ * 16 + (lane & 15);
    bbase[in_] = r * 128; bsel[in_] = r & 7;
  }
  const int kchunk = lane >> 4;

  f32x4 accg[4][2] = {};
  f32x4 accu[4][2] = {};

  auto stageA = [&](const f16* src, f16* dst) {
#pragma unroll
    for (int i = 0; i < 4; ++i)
      g2lds16(src + (size_t)i * 64 * HIDDEN, (char*)dst + aoff + i * 8192);
  };
  auto loadB = [&](int ktn, uint4& w0, uint4& w1,
                   float& s0f, float& z0f, float& s1f, float& z1f) {
    w0 = *(const uint4*)(qp + (size_t)ktn * 32);
    w1 = *(const uint4*)(qp + (size_t)32 * (HIDDEN / 2) + (size_t)ktn * 32);
    s0f = sp[ktn]; z0f = zp[ktn];
    s1f = sp[32 * NG1 + ktn]; z1f = zp[32 * NG1 + ktn];
  };
  auto writeB = [&](uint4 w0, uint4 w1, float s0f, float z0f, float s1f, float z1f) {
    __half2 s0 = __float2half2_rn(s0f), n0 = __float2half2_rn(-z0f * s0f);
    __half2 s1 = __float2half2_rn(s1f), n1 = __float2half2_rn(-z1f * s1f);
    uint4 o0, o1;
    o0.x = dq2(w0.x, s0, n0); o0.y = dq2(w0.y, s0, n0);
    o0.z = dq2(w0.z, s0, n0); o0.w = dq2(w0.w, s0, n0);
    o1.x = dq2(w1.x, s1, n1); o1.y = dq2(w1.y, s1, n1);
    o1.z = dq2(w1.z, s1, n1); o1.w = dq2(w1.w, s1, n1);
    *(uint4*)(lb + bws0) = o0;
    *(uint4*)(lb + bws0 + 32 * 128) = o1;
  };
  auto compute = [&](const f16* lA) {
#pragma unroll
    for (int ks = 0; ks < 2; ++ks) {
      int kc = ks * 4 + kchunk;
      f16x8 a[4], bg[2], bu[2];
#pragma unroll
      for (int im = 0; im < 4; ++im)
        a[im] = *(const f16x8*)((const char*)lA + abase[im] + ((kc ^ asel[im]) << 4));
#pragma unroll
      for (int in_ = 0; in_ < 2; ++in_) {
        bg[in_] = *(const f16x8*)(lBg + bbase[in_] + ((kc ^ bsel[in_]) << 4));
        bu[in_] = *(const f16x8*)(lBu + bbase[in_] + ((kc ^ bsel[in_]) << 4));
      }
#pragma unroll
      for (int im = 0; im < 4; ++im)
#pragma unroll
        for (int in_ = 0; in_ < 2; ++in_) {
          accg[im][in_] = __builtin_amdgcn_mfma_f32_16x16x32_f16(a[im], bg[in_], accg[im][in_], 0, 0, 0);
          accu[im][in_] = __builtin_amdgcn_mfma_f32_16x16x32_f16(a[im], bu[in_], accu[im][in_], 0, 0, 0);
        }
    }
  };

  stageA(aptr, lA0);
  {
    uint4 w0, w1; float s0f, z0f, s1f, z1f;
    loadB(0, w0, w1, s0f, z0f, s1f, z1f);
    writeB(w0, w1, s0f, z0f, s1f, z1f);
  }
  __syncthreads();

  for (int kt = 0; kt < NG1 - 1; ++kt) {
    stageA(aptr + (size_t)(kt + 1) * 64, (kt & 1) ? lA0 : lA1);
    uint4 w0, w1; float s0f, z0f, s1f, z1f;
    loadB(kt + 1, w0, w1, s0f, z0f, s1f, z1f);
    compute((kt & 1) ? lA1 : lA0);
    __syncthreads();
    writeB(w0, w1, s0f, z0f, s1f, z1f);
    __syncthreads();
  }
  compute(((NG1 - 1) & 1) ? lA1 : lA0);

#pragma unroll
  for (int im = 0; im < 4; ++im)
#pragma unroll
    for (int in_ = 0; in_ < 2; ++in_)
#pragma unroll
      for (int r = 0; r < 4; ++r) {
        int row = bm * 256 + wm * 64 + im * 16 + (lane >> 4) * 4 + r;
        int col = bn * 64 + wn * 32 + in_ * 16 + (lane & 15);
        float g = accg[im][in_][r];
        float u = accu[im][in_][r];
        float hv = (g / (1.0f + __expf(-g))) * u;
        h[(size_t)row * INTER + col] = (f16)hv;
      }
}

__global__ __launch_bounds__(512, 4) void gemm_down_q(
    const f16* __restrict__ h, const uint32_t* __restrict__ dq_,
    const float* __restrict__ dsc, const float* __restrict__ dz,
    float* __restrict__ out) {
  extern __shared__ char smem[];
  f16* lA0 = (f16*)smem;
  f16* lA1 = (f16*)(smem + 32768);
  char* lB = smem + 65536;
  const int tid = threadIdx.x, lane = tid & 63, wave = tid >> 6;
  const int bm = blockIdx.x, bn = blockIdx.y;
  const int wm = wave >> 1, wn = wave & 1;

  const int arow0 = tid >> 3;
  const int ak8s  = (tid & 7) ^ (arow0 & 7);
  const f16* aptr = h + (size_t)(bm * 256 + arow0) * INTER + ak8s * 8;
  const int aoff = tid * 16;

  const int brow0 = tid >> 3;
  const uint32_t* qp = dq_ + (size_t)(bn * 128 + brow0) * (INTER / 2) + (tid & 7) * 4;
  const float* sp = dsc + (size_t)(bn * 128 + brow0) * NG2;
  const float* zp = dz + (size_t)(bn * 128 + brow0) * NG2;
  const int bws0 = brow0 * 128 + (((tid & 7) ^ (brow0 & 7)) << 4);

  int abase[4], asel[4];
#pragma unroll
  for (int im = 0; im < 4; ++im) {
    int r = wm * 64 + im * 16 + (lane & 15);
    abase[im] = r * 128; asel[im] = r & 7;
  }
  int bbase[4], bsel[4];
#pragma unroll
  for (int in_ = 0; in_ < 4; ++in_) {
    int r = wn * 64 + in_ * 16 + (lane & 15);
    bbase[in_] = r * 128; bsel[in_] = r & 7;
  }
  const int kchunk = lane >> 4;

  f32x4 acc[4][4] = {};

  auto stageA = [&](const f16* src, f16* dst) {
#pragma unroll
    for (int i = 0; i < 4; ++i)
      g2lds16(src + (size_t)i * 64 * INTER, (char*)dst + aoff + i * 8192);
  };
  auto loadB = [&](int ktn, uint4& w0, uint4& w1,
                   float& s0f, float& z0f, float& s1f, float& z1f) {
    w0 = *(const uint4*)(qp + (size_t)ktn * 32);
    w1 = *(const uint4*)(qp + (size_t)64 * (INTER / 2) + (size_t)ktn * 32);
    s0f = sp[ktn]; z0f = zp[ktn];
    s1f = sp[64 * NG2 + ktn]; z1f = zp[64 * NG2 + ktn];
  };
  auto writeB = [&](uint4 w0, uint4 w1, float s0f, float z0f, float s1f, float z1f) {
    __half2 s0 = __float2half2_rn(s0f), n0 = __float2half2_rn(-z0f * s0f);
    __half2 s1 = __float2half2_rn(s1f), n1 = __float2half2_rn(-z1f * s1f);
    uint4 o0, o1;
    o0.x = dq2(w0.x, s0, n0); o0.y = dq2(w0.y, s0, n0);
    o0.z = dq2(w0.z, s0, n0); o0.w = dq2(w0.w, s0, n0);
    o1.x = dq2(w1.x, s1, n1); o1.y = dq2(w1.y, s1, n1);
    o1.z = dq2(w1.z, s1, n1); o1.w = dq2(w1.w, s1, n1);
    *(uint4*)(lB + bws0) = o0;
    *(uint4*)(lB + bws0 + 64 * 128) = o1;
  };
  auto compute = [&](const f16* lA) {
#pragma unroll
    for (int ks = 0; ks < 2; ++ks) {
      int kc = ks * 4 + kchunk;
      f16x8 a[4], b[4];
#pragma unroll
      for (int im = 0; im < 4; ++im)
        a[im] = *(const f16x8*)((const char*)lA + abase[im] + ((kc ^ asel[im]) << 4));
#pragma unroll
      for (int in_ = 0; in_ < 4; ++in_)
        b[in_] = *(const f16x8*)(lB + bbase[in_] + ((kc ^ bsel[in_]) << 4));
#pragma unroll
      for (int im = 0; im < 4; ++im)
#pragma unroll
        for (int in_ = 0; in_ < 4; ++in_)
          acc[im][in_] = __builtin_amdgcn_mfma_f32_16x16x32_f16(a[im], b[in_], acc[im][in_], 0, 0, 0);
    }
  };

  stageA(aptr, lA0);
  {
    uint4 w0, w1; float s0f, z0f, s1f, z1f;
    loadB(0, w0, w1, s0f, z0f, s1f, z1f);
    writeB(w0, w1, s0f, z0f, s1f, z1f);
  }
  __syncthreads();

  for (int kt = 0; kt < NG2 - 1; ++kt) {
    stageA(aptr + (size_t)(kt + 1) * 64, (kt & 1) ? lA0 : lA1);
    uint4 w0, w1; float s0f, z0f, s1f, z1f;
    loadB(kt + 1, w0, w1, s0f, z0f, s1f, z1f);
    compute((kt & 1) ? lA1 : lA0);
    __syncthreads();
    writeB(w0, w1, s0f, z0f, s1f, z1f);
    __syncthreads();
  }
  compute(((NG2 - 1) & 1) ? lA1 : lA0);

#pragma unroll
  for (int im = 0; im < 4; ++im)
#pragma unroll
    for (int in_ = 0; in_ < 4; ++in_)
#pragma unroll
      for (int r = 0; r < 4; ++r) {
        int row = bm * 256 + wm * 64 + im * 16 + (lane >> 4) * 4 + r;
        int col = bn * 128 + wn * 64 + in_ * 16 + (lane & 15);
        out[(size_t)row * HIDDEN + col] = acc[im][in_][r];
      }
}

// ------------------------------------------------------------------- launcher
extern "C" void kernel_launch(void* const* d_in, const int* in_sizes, int n_in,
                              void* d_out, int out_size, void* d_ws, size_t ws_size,
                              hipStream_t stream) {
  const float*    x   = (const float*)d_in[0];
  const uint32_t* gq  = (const uint32_t*)d_in[1];
  const uint32_t* uq  = (const uint32_t*)d_in[2];
  const uint32_t* dqw = (const uint32_t*)d_in[3];
  const float*    gs  = (const float*)d_in[4];
  const float*    gz  = (const float*)d_in[5];
  const float*    us  = (const float*)d_in[6];
  const float*    uz  = (const float*)d_in[7];
  const float*    dsc = (const float*)d_in[8];
  const float*    dzz = (const float*)d_in[9];

  const size_t XH = (size_t)NTOK * HIDDEN * 2;          // 33.6 MB
  const size_t HB = (size_t)NTOK * INTER * 2;           // 90.2 MB
  const size_t WB = (size_t)INTER * HIDDEN * 2;         // 90.2 MB
  f16* xh   = (f16*)d_ws;
  f16* hbuf = (f16*)((char*)d_ws + XH);
  float* out = (float*)d_out;

  cvt_x<<<dim3((NTOK * HIDDEN) / (256 * 8)), 256, 0, stream>>>(x, xh);

  if (ws_size >= XH + HB + 2 * WB) {
    // fast path: dequant once, 256-tile f16 GEMMs (1 block/CU, 128KB LDS)
    f16* W1 = (f16*)((char*)d_ws + XH + HB);            // gate, later down
    f16* W2 = (f16*)((char*)d_ws + XH + HB + WB);       // up
    const int LDS_BIG = 128 * 1024;
    (void)hipFuncSetAttribute((const void*)gemm_gateup2,
                              hipFuncAttributeMaxDynamicSharedMemorySize, LDS_BIG);
    (void)hipFuncSetAttribute((const void*)gemm_down2,
                              hipFuncAttributeMaxDynamicSharedMemorySize, LDS_BIG);
    deq_w<<<dim3((INTER * NG1) / 256), 256, 0, stream>>>(gq, gs, gz, W1);
    deq_w<<<dim3((INTER * NG1) / 256), 256, 0, stream>>>(uq, us, uz, W2);
    gemm_gateup2<<<dim3(NTOK / 256, INTER / 128), 512, LDS_BIG, stream>>>(
        xh, W1, W2, hbuf);
    deq_w<<<dim3((HIDDEN * NG2) / 256), 256, 0, stream>>>(dqw, dsc, dzz, W1);
    gemm_down2<<<dim3(NTOK / 256, HIDDEN / 256), 512, LDS_BIG, stream>>>(
        hbuf, W1, out);
  } else {
    // fallback: round-0 proven kernels (dequant in-GEMM)
    const int LDS_Q = 80 * 1024;
    (void)hipFuncSetAttribute((const void*)gemm_gateup_q,
                              hipFuncAttributeMaxDynamicSharedMemorySize, LDS_Q);
    (void)hipFuncSetAttribute((const void*)gemm_down_q,
                              hipFuncAttributeMaxDynamicSharedMemorySize, LDS_Q);
    gemm_gateup_q<<<dim3(NTOK / 256, INTER / 64), 512, LDS_Q, stream>>>(
        xh, gq, uq, gs, gz, us, uz, hbuf);
    gemm_down_q<<<dim3(NTOK / 256, HIDDEN / 128), 512, LDS_Q, stream>>>(
        hbuf, dqw, dsc, dzz, out);
  }
}